// Round 6
// baseline (784.269 us; speedup 1.0000x reference)
//
#include <hip/hip_runtime.h>
#include <hip/hip_cooperative_groups.h>
#include <math.h>

namespace cg = cooperative_groups;

#define DIM 394
#define KP  416      // padded K = 13*32
#define NT  13       // K-steps
#define NP  448      // padded N = 28*16
#define BN_EPS 1e-5f

typedef __bf16 bf16x8 __attribute__((ext_vector_type(8)));
typedef float  f32x4  __attribute__((ext_vector_type(4)));

// wave-uniform layout probe: int64 edge_index has all odd 32-bit words == 0
__device__ inline bool edges_are_int32(const int* ei) {
    int l = threadIdx.x & 63;
    unsigned long long b = __ballot(ei[2 * l + 1] != 0);
    return b != 0ULL;
}

// ---------------------------------------------------------------------------
// ws layout (floats): deg[n] (becomes dinv) | y[2n] | xs2[2n] | (align) Bp|Pk|Ok
// ---------------------------------------------------------------------------

// ONE cooperative kernel for the whole edge pipeline:
//   phase1: init deg/y + pack Pk/Ok + pack B fragments
//   phase2: degree count (device atomics)
//   phase3: dinv + xs2 = dinv*x
//   phase4: scatter y[d] += xs2[s]
__global__ __launch_bounds__(256)
void edge_coop(const int* __restrict__ ei, const float2* __restrict__ x2,
               const float* __restrict__ Wg, const float* __restrict__ bg,
               const float* __restrict__ gamma, const float* __restrict__ beta,
               const float* __restrict__ mean, const float* __restrict__ var,
               const float* __restrict__ fcw,
               float* __restrict__ deg, float* __restrict__ y,
               float2* __restrict__ xs2,
               float4* __restrict__ Pk, float* __restrict__ Ok,
               bf16x8* __restrict__ Bp, int n, int e) {
    cg::grid_group grid = cg::this_grid();
    int gtid = blockIdx.x * blockDim.x + threadIdx.x;
    int gstride = gridDim.x * blockDim.x;
    bool is32 = edges_are_int32(ei);

    // ---- phase 1: init + constant packing ----
    for (int i = gtid; i < n; i += gstride) {
        deg[i] = 1.0f;                   // self-loop
        y[2 * i] = 0.0f;
        y[2 * i + 1] = 0.0f;
    }
    for (int k = gtid; k < KP; k += gstride) {
        float4 p = make_float4(0.f, 0.f, 0.f, 0.f);
        float o = 0.f;
        if (k < DIM) {
            p.x = Wg[2 * k];
            p.y = Wg[2 * k + 1];
            p.z = bg[k];
            float s = gamma[k] * rsqrtf(var[k] + BN_EPS);
            p.w = s;
            o = beta[k] - s * mean[k];
        }
        Pk[k] = p;
        Ok[k] = o;
    }
    for (int idx = gtid; idx < NT * 4 * NP; idx += gstride) {
        int col = idx % NP;
        int r   = idx / NP;              // ks*4 + kc
        int k0  = r * 8;
        bf16x8 v;
        #pragma unroll
        for (int q = 0; q < 8; ++q) {
            int k = k0 + q;
            float f = (col < DIM && k < DIM) ? fcw[col * DIM + k] : 0.0f;
            v[q] = (__bf16)f;
        }
        Bp[idx] = v;
    }
    __threadfence();
    grid.sync();

    // ---- phase 2: degree count ----
    for (int i0 = gtid * 4; i0 < e; i0 += gstride * 4) {
        if (i0 + 4 <= e) {
            int d0, d1, d2, d3;
            if (is32) {
                int4 v = *reinterpret_cast<const int4*>(&ei[e + i0]);
                d0 = v.x; d1 = v.y; d2 = v.z; d3 = v.w;
            } else {
                int4 a = *reinterpret_cast<const int4*>(&ei[2 * (e + i0)]);
                int4 b = *reinterpret_cast<const int4*>(&ei[2 * (e + i0) + 4]);
                d0 = a.x; d1 = a.z; d2 = b.x; d3 = b.z;
            }
            atomicAdd(&deg[d0], 1.0f);
            atomicAdd(&deg[d1], 1.0f);
            atomicAdd(&deg[d2], 1.0f);
            atomicAdd(&deg[d3], 1.0f);
        } else {
            for (int j = 0; j < 4 && i0 + j < e; ++j) {
                int d = is32 ? ei[e + i0 + j] : ei[2 * (e + i0 + j)];
                atomicAdd(&deg[d], 1.0f);
            }
        }
    }
    __threadfence();
    grid.sync();
    __threadfence();

    // ---- phase 3: dinv + xs2 ----
    for (int i = gtid; i < n; i += gstride) {
        float di = rsqrtf(deg[i]);
        deg[i] = di;
        float2 xv = x2[i];
        xs2[i] = make_float2(di * xv.x, di * xv.y);
    }
    __threadfence();
    grid.sync();
    __threadfence();

    // ---- phase 4: scatter ----
    for (int i0 = gtid * 4; i0 < e; i0 += gstride * 4) {
        if (i0 + 4 <= e) {
            int s0, s1, s2, s3, d0, d1, d2, d3;
            if (is32) {
                int4 sv = *reinterpret_cast<const int4*>(&ei[i0]);
                int4 dv = *reinterpret_cast<const int4*>(&ei[e + i0]);
                s0 = sv.x; s1 = sv.y; s2 = sv.z; s3 = sv.w;
                d0 = dv.x; d1 = dv.y; d2 = dv.z; d3 = dv.w;
            } else {
                int4 a = *reinterpret_cast<const int4*>(&ei[2 * i0]);
                int4 b = *reinterpret_cast<const int4*>(&ei[2 * i0 + 4]);
                int4 c = *reinterpret_cast<const int4*>(&ei[2 * (e + i0)]);
                int4 d = *reinterpret_cast<const int4*>(&ei[2 * (e + i0) + 4]);
                s0 = a.x; s1 = a.z; s2 = b.x; s3 = b.z;
                d0 = c.x; d1 = c.z; d2 = d.x; d3 = d.z;
            }
            float2 m0 = xs2[s0], m1 = xs2[s1], m2 = xs2[s2], m3 = xs2[s3];
            atomicAdd(&y[2 * d0], m0.x); atomicAdd(&y[2 * d0 + 1], m0.y);
            atomicAdd(&y[2 * d1], m1.x); atomicAdd(&y[2 * d1 + 1], m1.y);
            atomicAdd(&y[2 * d2], m2.x); atomicAdd(&y[2 * d2 + 1], m2.y);
            atomicAdd(&y[2 * d3], m3.x); atomicAdd(&y[2 * d3 + 1], m3.y);
        } else {
            for (int j = 0; j < 4 && i0 + j < e; ++j) {
                int s = is32 ? ei[i0 + j]     : ei[2 * (i0 + j)];
                int d = is32 ? ei[e + i0 + j] : ei[2 * (e + i0 + j)];
                float2 m = xs2[s];
                atomicAdd(&y[2 * d],     m.x);
                atomicAdd(&y[2 * d + 1], m.y);
            }
        }
    }
}

// ---------------------------------------------------------------------------
// Fused: h = BN(relu(GCN)) on-the-fly -> bf16 MFMA GEMM -> +fc_b
//        -> z store + log_softmax store. 256 thr / 4 waves, BM=64, BN=448.
// B fragments read DIRECTLY global->VGPR (Bp is L2-resident, 256B-coalesced),
// register double-buffered. Only As (8KB) lives in LDS.
// ---------------------------------------------------------------------------
__global__ __launch_bounds__(256, 2)
void gemm_fused(const float* __restrict__ dinv, const float* __restrict__ y,
                const float2* __restrict__ xs2,
                const float4* __restrict__ Pk, const float* __restrict__ Ok,
                const bf16x8* __restrict__ Bp, const float* __restrict__ fcb,
                float* __restrict__ outp, float* __restrict__ z, int n) {
    __shared__ bf16x8 As[2][256];    // [kc(4)][row(64)] per buffer, 8 KB total

    int tid = threadIdx.x;
    int wv  = tid >> 6;
    int l   = tid & 63;
    int cg_ = tid & 15;
    int kg  = l >> 4;
    int row0 = blockIdx.x * 64;

    int gi = row0 + l;
    float y0 = 0.f, y1 = 0.f;
    if (gi < n) {
        float di = dinv[gi];
        float2 yv = *reinterpret_cast<const float2*>(&y[2 * gi]);
        float2 xv = xs2[gi];
        y0 = di * (yv.x + xv.x);
        y1 = di * (yv.y + xv.y);
    }

    f32x4 acc[4][7];
    #pragma unroll
    for (int a = 0; a < 4; ++a)
        #pragma unroll
        for (int b = 0; b < 7; ++b)
            acc[a][b] = (f32x4){0.f, 0.f, 0.f, 0.f};

    auto stageA = [&](int ks, int buf) {
        int kb = ks * 32 + wv * 8;
        bf16x8 hv;
        #pragma unroll
        for (int q = 0; q < 8; ++q) {
            float4 p = Pk[kb + q];
            float t = fmaf(y0, p.x, fmaf(y1, p.y, p.z));
            t = fmaxf(t, 0.f);
            hv[q] = (__bf16)fmaf(p.w, t, Ok[kb + q]);
        }
        As[buf][wv * 64 + l] = hv;
    };

    // lane-fixed B base: fragment (ks, ct) is at bptr[ks*4*448 + ct*16]
    const bf16x8* bptr = Bp + (kg * 448 + wv * 112 + cg_);

    bf16x8 Bcur[7], Bnxt[7];
    #pragma unroll
    for (int c = 0; c < 7; ++c) Bcur[c] = bptr[c * 16];
    stageA(0, 0);
    __syncthreads();

    int buf = 0;
    for (int ks = 0; ks < NT; ++ks) {
        if (ks < NT - 1) {
            const bf16x8* bn = bptr + (size_t)(ks + 1) * (4 * 448);
            #pragma unroll
            for (int c = 0; c < 7; ++c) Bnxt[c] = bn[c * 16];
            stageA(ks + 1, buf ^ 1);
        }
        bf16x8 af[4];
        #pragma unroll
        for (int rt = 0; rt < 4; ++rt)
            af[rt] = As[buf][kg * 64 + rt * 16 + cg_];
        #pragma unroll
        for (int ct = 0; ct < 7; ++ct)
            #pragma unroll
            for (int rt = 0; rt < 4; ++rt)
                acc[rt][ct] = __builtin_amdgcn_mfma_f32_16x16x32_bf16(
                                  af[rt], Bcur[ct], acc[rt][ct], 0, 0, 0);
        __syncthreads();
        #pragma unroll
        for (int c = 0; c < 7; ++c) Bcur[c] = Bnxt[c];
        buf ^= 1;
    }

    // ---------------- epilogue: bias + log_softmax + stores ----------------
    float* redm = (float*)&As[0][0];
    float* reds = redm + 256;

    int colb = wv * 112;
    float bias[7];
    bool  cv[7];
    #pragma unroll
    for (int ct = 0; ct < 7; ++ct) {
        int c = colb + ct * 16 + cg_;
        cv[ct] = (c < DIM);
        bias[ct] = cv[ct] ? fcb[c] : 0.f;
    }
    #pragma unroll
    for (int rt = 0; rt < 4; ++rt)
        #pragma unroll
        for (int ct = 0; ct < 7; ++ct)
            acc[rt][ct] = acc[rt][ct] + bias[ct];

    f32x4 mx[4];
    #pragma unroll
    for (int rt = 0; rt < 4; ++rt) {
        f32x4 m = (f32x4){-1e30f, -1e30f, -1e30f, -1e30f};
        #pragma unroll
        for (int ct = 0; ct < 7; ++ct) {
            if (!cv[ct]) continue;
            #pragma unroll
            for (int j = 0; j < 4; ++j) m[j] = fmaxf(m[j], acc[rt][ct][j]);
        }
        #pragma unroll
        for (int msk = 1; msk < 16; msk <<= 1)
            #pragma unroll
            for (int j = 0; j < 4; ++j)
                m[j] = fmaxf(m[j], __shfl_xor(m[j], msk));
        mx[rt] = m;
    }
    if (cg_ == 0) {
        #pragma unroll
        for (int rt = 0; rt < 4; ++rt)
            #pragma unroll
            for (int j = 0; j < 4; ++j)
                redm[(rt * 16 + kg * 4 + j) * 4 + wv] = mx[rt][j];
    }
    __syncthreads();
    f32x4 gm[4];
    #pragma unroll
    for (int rt = 0; rt < 4; ++rt)
        #pragma unroll
        for (int j = 0; j < 4; ++j) {
            int r = (rt * 16 + kg * 4 + j) * 4;
            gm[rt][j] = fmaxf(fmaxf(redm[r], redm[r + 1]),
                              fmaxf(redm[r + 2], redm[r + 3]));
        }

    f32x4 sm[4];
    #pragma unroll
    for (int rt = 0; rt < 4; ++rt) {
        f32x4 s = (f32x4){0.f, 0.f, 0.f, 0.f};
        #pragma unroll
        for (int ct = 0; ct < 7; ++ct) {
            if (!cv[ct]) continue;
            #pragma unroll
            for (int j = 0; j < 4; ++j)
                s[j] += __expf(acc[rt][ct][j] - gm[rt][j]);
        }
        #pragma unroll
        for (int msk = 1; msk < 16; msk <<= 1)
            #pragma unroll
            for (int j = 0; j < 4; ++j)
                s[j] += __shfl_xor(s[j], msk);
        sm[rt] = s;
    }
    if (cg_ == 0) {
        #pragma unroll
        for (int rt = 0; rt < 4; ++rt)
            #pragma unroll
            for (int j = 0; j < 4; ++j)
                reds[(rt * 16 + kg * 4 + j) * 4 + wv] = sm[rt][j];
    }
    __syncthreads();
    f32x4 lse[4];
    #pragma unroll
    for (int rt = 0; rt < 4; ++rt)
        #pragma unroll
        for (int j = 0; j < 4; ++j) {
            int r = (rt * 16 + kg * 4 + j) * 4;
            float t = reds[r] + reds[r + 1] + reds[r + 2] + reds[r + 3];
            lse[rt][j] = gm[rt][j] + __logf(t);
        }

    #pragma unroll
    for (int rt = 0; rt < 4; ++rt)
        #pragma unroll
        for (int j = 0; j < 4; ++j) {
            int grow = row0 + rt * 16 + kg * 4 + j;
            if (grow >= n) continue;
            size_t base = (size_t)grow * DIM;
            float L = lse[rt][j];
            #pragma unroll
            for (int ct = 0; ct < 7; ++ct) {
                if (!cv[ct]) continue;
                int c = colb + ct * 16 + cg_;
                float zv = acc[rt][ct][j];
                z[base + c]    = zv;
                outp[base + c] = zv - L;
            }
        }
}

// ---------------------------------------------------------------------------
extern "C" void kernel_launch(void* const* d_in, const int* in_sizes, int n_in,
                              void* d_out, int out_size, void* d_ws, size_t ws_size,
                              hipStream_t stream) {
    int n = in_sizes[0] / 2;       // 50000 nodes
    int e = in_sizes[1] / 2;       // 800000 edges

    const float2* x2   = (const float2*)d_in[0];
    const int*   ei    = (const int*)d_in[1];
    const float* Wg    = (const float*)d_in[2];
    const float* bg    = (const float*)d_in[3];
    const float* gamma = (const float*)d_in[4];
    const float* beta  = (const float*)d_in[5];
    const float* mean  = (const float*)d_in[6];
    const float* var   = (const float*)d_in[7];
    const float* fcw   = (const float*)d_in[8];
    const float* fcb   = (const float*)d_in[9];

    float* out = (float*)d_out;                 // [n, DIM] log_softmax
    float* z   = out + (size_t)n * DIM;         // [n, DIM] logits

    char* wsb = (char*)d_ws;
    float*  deg  = (float*)wsb;                         // n (becomes dinv)
    float*  y    = deg + n;                             // 2n
    float2* xs2  = (float2*)(y + 2 * (size_t)n);        // 2n floats
    size_t off = ((size_t)(5 * n) * 4 + 255) & ~(size_t)255;
    bf16x8* Bp = (bf16x8*)(wsb + off);                  // 13*4*448 * 16B
    off += (size_t)NT * 4 * NP * 16;
    float4* Pk = (float4*)(wsb + off);                  // KP * 16B
    off += (size_t)KP * 16;
    float* Ok  = (float*)(wsb + off);                   // KP * 4B

    void* args[] = {(void*)&ei, (void*)&x2, (void*)&Wg, (void*)&bg,
                    (void*)&gamma, (void*)&beta, (void*)&mean, (void*)&var,
                    (void*)&fcw, (void*)&deg, (void*)&y, (void*)&xs2,
                    (void*)&Pk, (void*)&Ok, (void*)&Bp, (void*)&n, (void*)&e};
    hipLaunchCooperativeKernel(reinterpret_cast<void*>(edge_coop),
                               dim3(1024), dim3(256), args, 0, stream);

    int gm = (n + 63) / 64;
    gemm_fused<<<gm, 256, 0, stream>>>(deg, y, xs2, Pk, Ok, Bp, fcb, out, z, n);
}

// Round 7
// 128.998 us; speedup vs baseline: 6.0797x; 6.0797x over previous
//
#include <hip/hip_runtime.h>
#include <math.h>

#define DIM 394
#define KP  416      // padded K = 13*32
#define NT  13       // K-steps
#define NP  448      // padded N = 28*16
#define BN_EPS 1e-5f
#define MAXD 96      // payload slots per node (P[Poisson(16) > 96] ~ 1e-50)

typedef __bf16 bf16x8 __attribute__((ext_vector_type(8)));
typedef float  f32x4  __attribute__((ext_vector_type(4)));

// wave-uniform layout probe: int64 edge_index has all odd 32-bit words == 0
__device__ inline bool edges_are_int32(const int* ei) {
    int l = threadIdx.x & 63;
    unsigned long long b = __ballot(ei[2 * l + 1] != 0);
    return b != 0ULL;
}

// ---------------------------------------------------------------------------
// ws layout: degc[n] u32 | yover[2n] f32 | ocnt[1]+pad | olist[e] uint2 |
//            payload[n*MAXD] u32 | (align 256) Bp | Pk | Ok
// ---------------------------------------------------------------------------

// block-role-split prep: zero degc/yover/ocnt, pack Pk/Ok, pack B fragments
__global__ void prep_kernel(const float* __restrict__ Wg, const float* __restrict__ bg,
                            const float* __restrict__ gamma, const float* __restrict__ beta,
                            const float* __restrict__ mean, const float* __restrict__ var,
                            const float* __restrict__ fcw,
                            uint4* __restrict__ zbase, float4* __restrict__ Pk,
                            float* __restrict__ Ok, bf16x8* __restrict__ Bp,
                            int z4, int zb) {
    int b = blockIdx.x, t = threadIdx.x;
    if (b < zb) {                        // zero degc + yover + ocnt
        int i = b * 256 + t;
        if (i < z4) zbase[i] = make_uint4(0u, 0u, 0u, 0u);
    } else if (b < zb + 2) {             // Pk/Ok: per-k GCN+BN constants
        int k = (b - zb) * 256 + t;
        if (k < KP) {
            float4 p = make_float4(0.f, 0.f, 0.f, 0.f);
            float o = 0.f;
            if (k < DIM) {
                p.x = Wg[2 * k];
                p.y = Wg[2 * k + 1];
                p.z = bg[k];
                float s = gamma[k] * rsqrtf(var[k] + BN_EPS);
                p.w = s;
                o = beta[k] - s * mean[k];
            }
            Pk[k] = p;
            Ok[k] = o;
        }
    } else {                             // B = fc_w^T packed bf16 fragments
        int idx = (b - zb - 2) * 256 + t;
        if (idx < NT * 4 * NP) {
            int col = idx % NP;
            int r   = idx / NP;          // ks*4 + kc
            int k0  = r * 8;
            bf16x8 v;
            #pragma unroll
            for (int q = 0; q < 8; ++q) {
                int k = k0 + q;
                float f = (col < DIM && k < DIM) ? fcw[col * DIM + k] : 0.0f;
                v[q] = (__bf16)f;
            }
            Bp[idx] = v;
        }
    }
}

// place: one pass = degree count (ticket) + CSR-slot fill. 1 atomic/edge.
__global__ void place_kernel(const int* __restrict__ ei,
                             unsigned* __restrict__ degc,
                             unsigned* __restrict__ payload,
                             unsigned* __restrict__ ocnt,
                             uint2* __restrict__ olist, int e) {
    bool is32 = edges_are_int32(ei);
    int i0 = (blockIdx.x * blockDim.x + threadIdx.x) * 4;
    if (i0 >= e) return;
    int s[4], d[4];
    int cnt = 4;
    if (i0 + 4 <= e) {
        if (is32) {
            int4 sv = *reinterpret_cast<const int4*>(&ei[i0]);
            int4 dv = *reinterpret_cast<const int4*>(&ei[e + i0]);
            s[0] = sv.x; s[1] = sv.y; s[2] = sv.z; s[3] = sv.w;
            d[0] = dv.x; d[1] = dv.y; d[2] = dv.z; d[3] = dv.w;
        } else {
            int4 a = *reinterpret_cast<const int4*>(&ei[2 * i0]);
            int4 b = *reinterpret_cast<const int4*>(&ei[2 * i0 + 4]);
            int4 c = *reinterpret_cast<const int4*>(&ei[2 * (e + i0)]);
            int4 dd = *reinterpret_cast<const int4*>(&ei[2 * (e + i0) + 4]);
            s[0] = a.x; s[1] = a.z; s[2] = b.x; s[3] = b.z;
            d[0] = c.x; d[1] = c.z; d[2] = dd.x; d[3] = dd.z;
        }
    } else {
        cnt = e - i0;
        for (int j = 0; j < cnt; ++j) {
            s[j] = is32 ? ei[i0 + j]     : ei[2 * (i0 + j)];
            d[j] = is32 ? ei[e + i0 + j] : ei[2 * (e + i0 + j)];
        }
    }
    #pragma unroll
    for (int j = 0; j < 4; ++j) {
        if (j >= cnt) break;
        unsigned t = atomicAdd(&degc[d[j]], 1u);
        if (t < MAXD) {
            payload[(size_t)d[j] * MAXD + t] = (unsigned)s[j];
        } else {
            unsigned o = atomicAdd(ocnt, 1u);
            olist[o] = make_uint2((unsigned)s[j], (unsigned)d[j]);
        }
    }
}

// cleanup: drain overflow edges (expected count 0) into yover via atomics
__global__ void cleanup_kernel(const uint2* __restrict__ olist,
                               const unsigned* __restrict__ ocnt,
                               const unsigned* __restrict__ degc,
                               const float2* __restrict__ x2,
                               float* __restrict__ yover) {
    unsigned cnt = *ocnt;
    int gstride = gridDim.x * blockDim.x;
    for (unsigned i = blockIdx.x * blockDim.x + threadIdx.x; i < cnt; i += gstride) {
        uint2 sd = olist[i];
        float ds = rsqrtf(1.0f + (float)degc[sd.x]);
        float2 xv = x2[sd.x];
        atomicAdd(&yover[2 * sd.y],     ds * xv.x);
        atomicAdd(&yover[2 * sd.y + 1], ds * xv.y);
    }
}

// ---------------------------------------------------------------------------
// Fused: segment gather-sum (GCN aggregation) -> h = BN(relu(.)) on the fly
//        -> bf16 MFMA GEMM -> +fc_b -> z store + log_softmax store.
// 256 thr / 4 waves, BM=64, BN=448. B frags direct global->VGPR (L2-resident),
// register double-buffered; As (8KB) + red (2KB) in LDS.
// ---------------------------------------------------------------------------
__global__ __launch_bounds__(256, 2)
void gemm_fused(const float2* __restrict__ x2, const unsigned* __restrict__ degc,
                const unsigned* __restrict__ payload, const float* __restrict__ yover,
                const float4* __restrict__ Pk, const float* __restrict__ Ok,
                const bf16x8* __restrict__ Bp, const float* __restrict__ fcb,
                float* __restrict__ outp, float* __restrict__ z, int n) {
    __shared__ bf16x8 As[2][256];    // [kc(4)][row(64)] per buffer, 8 KB
    __shared__ float2 red[64][4];    // gather partial sums, 2 KB

    int tid = threadIdx.x;
    int wv  = tid >> 6;              // wave id == gather part id
    int l   = tid & 63;              // row within tile
    int cg_ = tid & 15;
    int kg  = l >> 4;
    int row0 = blockIdx.x * 64;
    int gi = row0 + l;

    // ---- fused GCN aggregation: y = dinv*(segment_sum + dinv*x) ----
    float y0 = 0.f, y1 = 0.f;
    {
        float2 psum = make_float2(0.f, 0.f);
        float dinv_i = 0.f;
        float2 xi = make_float2(0.f, 0.f);
        if (gi < n) {
            unsigned dg = degc[gi];
            dinv_i = rsqrtf(1.0f + (float)dg);
            xi = x2[gi];
            unsigned m = dg < MAXD ? dg : MAXD;
            const unsigned* pl = payload + (size_t)gi * MAXD;
            for (unsigned t = wv; t < m; t += 4) {
                unsigned s = pl[t];
                float2 xv = x2[s];
                float ds = rsqrtf(1.0f + (float)degc[s]);
                psum.x = fmaf(ds, xv.x, psum.x);
                psum.y = fmaf(ds, xv.y, psum.y);
            }
            if (wv == 0) {
                psum.x += yover[2 * gi];
                psum.y += yover[2 * gi + 1];
            }
        }
        red[l][wv] = psum;
        __syncthreads();
        if (gi < n) {
            float sx = red[l][0].x + red[l][1].x + red[l][2].x + red[l][3].x;
            float sy = red[l][0].y + red[l][1].y + red[l][2].y + red[l][3].y;
            y0 = dinv_i * (sx + dinv_i * xi.x);
            y1 = dinv_i * (sy + dinv_i * xi.y);
        }
    }

    f32x4 acc[4][7];
    #pragma unroll
    for (int a = 0; a < 4; ++a)
        #pragma unroll
        for (int b = 0; b < 7; ++b)
            acc[a][b] = (f32x4){0.f, 0.f, 0.f, 0.f};

    auto stageA = [&](int ks, int buf) {
        int kb = ks * 32 + wv * 8;
        bf16x8 hv;
        #pragma unroll
        for (int q = 0; q < 8; ++q) {
            float4 p = Pk[kb + q];
            float t = fmaf(y0, p.x, fmaf(y1, p.y, p.z));
            t = fmaxf(t, 0.f);
            hv[q] = (__bf16)fmaf(p.w, t, Ok[kb + q]);
        }
        As[buf][wv * 64 + l] = hv;
    };

    // lane-fixed B base: fragment (ks, ct) is at bptr[ks*4*448 + ct*16]
    const bf16x8* bptr = Bp + (kg * 448 + wv * 112 + cg_);

    bf16x8 Bcur[7], Bnxt[7];
    #pragma unroll
    for (int c = 0; c < 7; ++c) Bcur[c] = bptr[c * 16];
    stageA(0, 0);
    __syncthreads();

    int buf = 0;
    for (int ks = 0; ks < NT; ++ks) {
        if (ks < NT - 1) {
            const bf16x8* bn = bptr + (size_t)(ks + 1) * (4 * 448);
            #pragma unroll
            for (int c = 0; c < 7; ++c) Bnxt[c] = bn[c * 16];
            stageA(ks + 1, buf ^ 1);
        }
        bf16x8 af[4];
        #pragma unroll
        for (int rt = 0; rt < 4; ++rt)
            af[rt] = As[buf][kg * 64 + rt * 16 + cg_];
        #pragma unroll
        for (int ct = 0; ct < 7; ++ct)
            #pragma unroll
            for (int rt = 0; rt < 4; ++rt)
                acc[rt][ct] = __builtin_amdgcn_mfma_f32_16x16x32_bf16(
                                  af[rt], Bcur[ct], acc[rt][ct], 0, 0, 0);
        __syncthreads();
        #pragma unroll
        for (int c = 0; c < 7; ++c) Bcur[c] = Bnxt[c];
        buf ^= 1;
    }

    // ---------------- epilogue: bias + log_softmax + stores ----------------
    float* redm = (float*)&As[0][0];
    float* reds = redm + 256;

    int colb = wv * 112;
    float bias[7];
    bool  cv[7];
    #pragma unroll
    for (int ct = 0; ct < 7; ++ct) {
        int c = colb + ct * 16 + cg_;
        cv[ct] = (c < DIM);
        bias[ct] = cv[ct] ? fcb[c] : 0.f;
    }
    #pragma unroll
    for (int rt = 0; rt < 4; ++rt)
        #pragma unroll
        for (int ct = 0; ct < 7; ++ct)
            acc[rt][ct] = acc[rt][ct] + bias[ct];

    f32x4 mx[4];
    #pragma unroll
    for (int rt = 0; rt < 4; ++rt) {
        f32x4 m = (f32x4){-1e30f, -1e30f, -1e30f, -1e30f};
        #pragma unroll
        for (int ct = 0; ct < 7; ++ct) {
            if (!cv[ct]) continue;
            #pragma unroll
            for (int j = 0; j < 4; ++j) m[j] = fmaxf(m[j], acc[rt][ct][j]);
        }
        #pragma unroll
        for (int msk = 1; msk < 16; msk <<= 1)
            #pragma unroll
            for (int j = 0; j < 4; ++j)
                m[j] = fmaxf(m[j], __shfl_xor(m[j], msk));
        mx[rt] = m;
    }
    if (cg_ == 0) {
        #pragma unroll
        for (int rt = 0; rt < 4; ++rt)
            #pragma unroll
            for (int j = 0; j < 4; ++j)
                redm[(rt * 16 + kg * 4 + j) * 4 + wv] = mx[rt][j];
    }
    __syncthreads();
    f32x4 gm[4];
    #pragma unroll
    for (int rt = 0; rt < 4; ++rt)
        #pragma unroll
        for (int j = 0; j < 4; ++j) {
            int r = (rt * 16 + kg * 4 + j) * 4;
            gm[rt][j] = fmaxf(fmaxf(redm[r], redm[r + 1]),
                              fmaxf(redm[r + 2], redm[r + 3]));
        }

    f32x4 sm[4];
    #pragma unroll
    for (int rt = 0; rt < 4; ++rt) {
        f32x4 s = (f32x4){0.f, 0.f, 0.f, 0.f};
        #pragma unroll
        for (int ct = 0; ct < 7; ++ct) {
            if (!cv[ct]) continue;
            #pragma unroll
            for (int j = 0; j < 4; ++j)
                s[j] += __expf(acc[rt][ct][j] - gm[rt][j]);
        }
        #pragma unroll
        for (int msk = 1; msk < 16; msk <<= 1)
            #pragma unroll
            for (int j = 0; j < 4; ++j)
                s[j] += __shfl_xor(s[j], msk);
        sm[rt] = s;
    }
    if (cg_ == 0) {
        #pragma unroll
        for (int rt = 0; rt < 4; ++rt)
            #pragma unroll
            for (int j = 0; j < 4; ++j)
                reds[(rt * 16 + kg * 4 + j) * 4 + wv] = sm[rt][j];
    }
    __syncthreads();
    f32x4 lse[4];
    #pragma unroll
    for (int rt = 0; rt < 4; ++rt)
        #pragma unroll
        for (int j = 0; j < 4; ++j) {
            int r = (rt * 16 + kg * 4 + j) * 4;
            float t = reds[r] + reds[r + 1] + reds[r + 2] + reds[r + 3];
            lse[rt][j] = gm[rt][j] + __logf(t);
        }

    #pragma unroll
    for (int rt = 0; rt < 4; ++rt)
        #pragma unroll
        for (int j = 0; j < 4; ++j) {
            int grow = row0 + rt * 16 + kg * 4 + j;
            if (grow >= n) continue;
            size_t base = (size_t)grow * DIM;
            float L = lse[rt][j];
            #pragma unroll
            for (int ct = 0; ct < 7; ++ct) {
                if (!cv[ct]) continue;
                int c = colb + ct * 16 + cg_;
                float zv = acc[rt][ct][j];
                z[base + c]    = zv;
                outp[base + c] = zv - L;
            }
        }
}

// ---------------------------------------------------------------------------
extern "C" void kernel_launch(void* const* d_in, const int* in_sizes, int n_in,
                              void* d_out, int out_size, void* d_ws, size_t ws_size,
                              hipStream_t stream) {
    int n = in_sizes[0] / 2;       // 50000 nodes
    int e = in_sizes[1] / 2;       // 800000 edges

    const float2* x2   = (const float2*)d_in[0];
    const int*   ei    = (const int*)d_in[1];
    const float* Wg    = (const float*)d_in[2];
    const float* bg    = (const float*)d_in[3];
    const float* gamma = (const float*)d_in[4];
    const float* beta  = (const float*)d_in[5];
    const float* mean  = (const float*)d_in[6];
    const float* var   = (const float*)d_in[7];
    const float* fcw   = (const float*)d_in[8];
    const float* fcb   = (const float*)d_in[9];

    float* out = (float*)d_out;                 // [n, DIM] log_softmax
    float* z   = out + (size_t)n * DIM;         // [n, DIM] logits

    char* wsb = (char*)d_ws;
    unsigned* degc  = (unsigned*)wsb;                   // n
    float*    yover = (float*)(degc + n);               // 2n
    unsigned* ocnt  = (unsigned*)(yover + 2 * (size_t)n); // 1 (+3 pad)
    uint2*    olist = (uint2*)(ocnt + 4);               // e entries
    unsigned* payload = (unsigned*)(olist + e);         // n*MAXD
    size_t off = (size_t)(3 * n + 4) * 4 + (size_t)e * 8 + (size_t)n * MAXD * 4;
    off = (off + 255) & ~(size_t)255;
    bf16x8* Bp = (bf16x8*)(wsb + off);                  // 13*4*448 * 16B
    off += (size_t)NT * 4 * NP * 16;
    float4* Pk = (float4*)(wsb + off);                  // KP * 16B
    off += (size_t)KP * 16;
    float* Ok  = (float*)(wsb + off);                   // KP * 4B

    int zwords = 3 * n + 4;                  // degc + yover + ocnt(+pad)
    int z4 = (zwords + 3) / 4;
    int zb = (z4 + 255) / 256;
    int prep_blocks = zb + 2 + (NT * 4 * NP + 255) / 256;
    int eb4 = (e / 4 + 255) / 256 + 1;

    prep_kernel<<<prep_blocks, 256, 0, stream>>>(Wg, bg, gamma, beta, mean, var,
                                                 fcw, (uint4*)degc, Pk, Ok, Bp,
                                                 z4, zb);
    place_kernel<<<eb4, 256, 0, stream>>>(ei, degc, payload, ocnt, olist, e);
    cleanup_kernel<<<64, 256, 0, stream>>>(olist, ocnt, degc, x2, yover);

    int gm = (n + 63) / 64;
    gemm_fused<<<gm, 256, 0, stream>>>(x2, degc, payload, yover, Pk, Ok, Bp,
                                       fcb, out, z, n);
}